// Round 10
// baseline (423.784 us; speedup 1.0000x reference)
//
#include <hip/hip_runtime.h>
#include <hip/hip_fp16.h>

// ---------------------------------------------------------------------------
// DUPLEX GAT, round 18.
//   - NEW schedule: init (zero + wprep) -> hist || gemm0 (independent once
//     wprep is out of hist; gemm blocks first in grid, hist's fire-and-forget
//     atomics tolerate the fused kernel's VGPR/LDS cost) -> scan -> fill ->
//     gather0 -> gemm1 -> gather1. Overlaps hist under gemm0 (~15-35us).
//   - NEW per-channel edge recs: am8/ph8 = {src, w} int2 arrays. Gather reads
//     8B/edge instead of 16B (dst + other-channel weight were dead weight):
//     -12.8MB FETCH per gather dispatch.
//   - gather: r13 fused lane-parallel coef shape (best measured); fill:
//     atomic-free via rank-from-hist (r17 win).
//   - 7 dispatches: init, hist||gemm0, scan, fill, gather0, gemm1, gather1.
// ---------------------------------------------------------------------------

typedef _Float16 f16x8 __attribute__((ext_vector_type(8)));
typedef float f32x4 __attribute__((ext_vector_type(4)));

struct GemmP { const void* X; const __half* Wt; const float *al, *ar; __half* Y; float *el, *er; };
struct ChP   { const __half* ft; const float *el, *er, *bias; const int2* ed; void* out; };

// Zero the counts+sync region AND convert/transpose the 4 weight matrices
// (Wt_m[nn][k] = half(W_m[k][nn])). Replaces hipMemsetAsync + in-hist wprep.
__global__ void init_kernel(int* __restrict__ zero, int nzero,
                            const float* __restrict__ W0a, const float* __restrict__ W0p,
                            const float* __restrict__ W1a, const float* __restrict__ W1p,
                            __half* __restrict__ Wt) {
  int i = blockIdx.x * 256 + threadIdx.x;  // grid = 256 blocks = 65536 threads
  if (i < nzero) zero[i] = 0;
  {
    int m = i >> 14, idx = i & 16383;
    const float* W = (m == 0) ? W0a : (m == 1) ? W0p : (m == 2) ? W1a : W1p;
    int nn = idx >> 7, k = idx & 127;
    Wt[(size_t)m * 16384 + nn * 128 + k] = __float2half_rn(W[k * 128 + nn]);
  }
}

// Single-pass exclusive scan, wave-parallel decoupled lookback.
// sync layout (ints): [0]=ticket; state[nb_stride] @ +64; agg @ +64+nb_stride;
// incl @ +64+2*nb_stride. All zeroed by init.
__global__ __launch_bounds__(256) void scan_kernel(const int* __restrict__ counts,
                                                   int* __restrict__ offsets,
                                                   int* __restrict__ sync,
                                                   int nb_stride, int n, int E) {
  __shared__ int lds[256];
  __shared__ int sbid, sprev;
  int* state = sync + 64;
  int* agg = state + nb_stride;
  int* incl = agg + nb_stride;
  int t = threadIdx.x;
  if (t == 0) sbid = atomicAdd(sync, 1);
  __syncthreads();
  int bid = sbid;
  int i = bid * 256 + t;
  int v = (i < n) ? counts[i] : 0;
  lds[t] = v;
  __syncthreads();
  for (int off = 1; off < 256; off <<= 1) {
    int x = (t >= off) ? lds[t - off] : 0;
    __syncthreads();
    lds[t] += x;
    __syncthreads();
  }
  int total = lds[255];
  if (t == 0) {
    if (bid == 0) {
      __hip_atomic_store(&incl[0], total, __ATOMIC_RELAXED, __HIP_MEMORY_SCOPE_AGENT);
      __hip_atomic_store(&state[0], 2, __ATOMIC_RELEASE, __HIP_MEMORY_SCOPE_AGENT);
      sprev = 0;
    } else {
      __hip_atomic_store(&agg[bid], total, __ATOMIC_RELAXED, __HIP_MEMORY_SCOPE_AGENT);
      __hip_atomic_store(&state[bid], 1, __ATOMIC_RELEASE, __HIP_MEMORY_SCOPE_AGENT);
    }
  }
  if (bid > 0 && t < 64) {  // wave 0: windowed lookback, 64 predecessors/round
    int run = 0;
    int base = bid - 1;
    while (true) {
      int idx = base - t;
      int st = 2, val = 0;
      if (idx >= 0) {
        do {
          st = __hip_atomic_load(&state[idx], __ATOMIC_ACQUIRE, __HIP_MEMORY_SCOPE_AGENT);
        } while (st == 0);
        val = (st == 2)
                  ? __hip_atomic_load(&incl[idx], __ATOMIC_RELAXED, __HIP_MEMORY_SCOPE_AGENT)
                  : __hip_atomic_load(&agg[idx], __ATOMIC_RELAXED, __HIP_MEMORY_SCOPE_AGENT);
      }
      unsigned long long done = __ballot(st == 2);
      int firstDone = (int)__ffsll(done) - 1;  // nearest block with inclusive prefix
      int contrib = (firstDone < 0) ? val : ((t <= firstDone) ? val : 0);
#pragma unroll
      for (int o = 1; o < 64; o <<= 1) contrib += __shfl_xor(contrib, o);
      run += contrib;
      if (firstDone >= 0) break;
      base -= 64;
    }
    if (t == 0) {
      __hip_atomic_store(&incl[bid], run + total, __ATOMIC_RELAXED, __HIP_MEMORY_SCOPE_AGENT);
      __hip_atomic_store(&state[bid], 2, __ATOMIC_RELEASE, __HIP_MEMORY_SCOPE_AGENT);
      sprev = run;
    }
  }
  __syncthreads();
  int prev = sprev;
  if (i < n) offsets[i] = prev + lds[t] - v;  // exclusive
  if (i == 0) offsets[n] = E;
}

// Atomic-free fill: pos = offs[dst] + rank[e]. Per-channel 8B records.
__global__ void fill_kernel(const int* __restrict__ src, const int* __restrict__ dst,
                            const float* __restrict__ exist, const float* __restrict__ am_exist,
                            const int* __restrict__ offs, const int* __restrict__ rank,
                            int2* __restrict__ am8, int2* __restrict__ ph8, int E) {
  int e = blockIdx.x * blockDim.x + threadIdx.x;
  if (e >= E) return;
  int d = dst[e];
  int pos = offs[d] + rank[e];
  int s = src[e];
  am8[pos] = make_int2(s, __float_as_int(am_exist[e]));
  ph8[pos] = make_int2(s, __float_as_int(exist[e]));
}

// Y(fp16) = fp16(X) @ fp16(W), fp32 MFMA acc; fused fp32 el/er epilogue.
// AFP16: A operand already fp16 (layer 1) vs fp32->fp16 staging (layer 0).
template <int AFP16>
__device__ __forceinline__ void gemm_body(GemmP p, int bx, int n) {
  constexpr int LDH = 72;   // staging stride (halves)
  constexpr int LDE = 136;  // epilogue stride (halves)
  __shared__ __half lds[2 * 128 * LDH];  // 36,864 B
  __half* As = lds;
  __half* Ws = lds + 128 * LDH;
  int t = threadIdx.x;
  int row0 = bx << 7;
  int wv = t >> 6, lane = t & 63;
  int m = lane & 15, q = lane >> 4;

  f32x4 acc[2][8];
#pragma unroll
  for (int rt = 0; rt < 2; ++rt)
#pragma unroll
    for (int ct = 0; ct < 8; ++ct) acc[rt][ct] = (f32x4){0.f, 0.f, 0.f, 0.f};

#pragma unroll
  for (int kh = 0; kh < 2; ++kh) {
    __syncthreads();  // protect previous phase's fragment reads
    if (AFP16) {
      const __half* Xh = (const __half*)p.X;
#pragma unroll
      for (int i = 0; i < 4; ++i) {
        int c = t + (i << 8);  // 0..1023 chunks of 8 halves
        int r = c >> 3, o8 = c & 7;
        uint4 v = make_uint4(0, 0, 0, 0);
        if (row0 + r < n)
          v = *(const uint4*)(Xh + (size_t)(row0 + r) * 128 + (kh << 6) + (o8 << 3));
        *(uint4*)(As + r * LDH + (o8 << 3)) = v;
      }
    } else {
      const float* Xf = (const float*)p.X;
#pragma unroll
      for (int i = 0; i < 8; ++i) {
        int c = t + (i << 8);  // 0..2047 float4-chunks
        int r = c >> 4, f4 = c & 15;
        float4 v = make_float4(0.f, 0.f, 0.f, 0.f);
        if (row0 + r < n)
          v = *(const float4*)(Xf + (size_t)(row0 + r) * 128 + (kh << 6) + (f4 << 2));
        union { __half h[4]; uint2 u; } pk;
        pk.h[0] = __float2half_rn(v.x); pk.h[1] = __float2half_rn(v.y);
        pk.h[2] = __float2half_rn(v.z); pk.h[3] = __float2half_rn(v.w);
        *(uint2*)(As + r * LDH + (f4 << 2)) = pk.u;
      }
    }
    // stage Wt: 128 n-rows x 64 k (already fp16)
#pragma unroll
    for (int i = 0; i < 4; ++i) {
      int c = t + (i << 8);
      int r = c >> 3, o8 = c & 7;
      uint4 v = *(const uint4*)(p.Wt + (size_t)r * 128 + (kh << 6) + (o8 << 3));
      *(uint4*)(Ws + r * LDH + (o8 << 3)) = v;
    }
    __syncthreads();
#pragma unroll
    for (int kc = 0; kc < 2; ++kc) {
      f16x8 a0 = *(const f16x8*)(As + (wv * 32 + m) * LDH + kc * 32 + q * 8);
      f16x8 a1 = *(const f16x8*)(As + (wv * 32 + 16 + m) * LDH + kc * 32 + q * 8);
#pragma unroll
      for (int ct = 0; ct < 8; ++ct) {
        f16x8 b = *(const f16x8*)(Ws + (ct * 16 + m) * LDH + kc * 32 + q * 8);
        acc[0][ct] = __builtin_amdgcn_mfma_f32_16x16x32_f16(a0, b, acc[0][ct], 0, 0, 0);
        acc[1][ct] = __builtin_amdgcn_mfma_f32_16x16x32_f16(a1, b, acc[1][ct], 0, 0, 0);
      }
    }
  }
  // ---- epilogue: acc -> LDS fp16 (C/D layout: col=lane&15, row=quad*4+reg) ----
  __syncthreads();
#pragma unroll
  for (int rt = 0; rt < 2; ++rt) {
    int rbase = wv * 32 + rt * 16 + q * 4;
#pragma unroll
    for (int ct = 0; ct < 8; ++ct) {
      int col = ct * 16 + m;
#pragma unroll
      for (int r = 0; r < 4; ++r)
        lds[(rbase + r) * LDE + col] = __float2half_rn(acc[rt][ct][r]);
    }
  }
  __syncthreads();
  // 2 threads per row: half = cols 0..63 / 64..127. ft store + el/er head-dots.
  {
    int r = t & 127;
    int half = t >> 7;
    int row = row0 + r;
    if (row < n) {
      float e0 = 0.f, e1 = 0.f, r0 = 0.f, r1 = 0.f;
#pragma unroll
      for (int i = 0; i < 8; ++i) {
        int cbase = half * 64 + i * 8;
        f16x8 v = *(const f16x8*)(lds + r * LDE + cbase);
        *(uint4*)(p.Y + (size_t)row * 128 + cbase) = *(const uint4*)&v;
#pragma unroll
        for (int j = 0; j < 8; ++j) {
          float f = (float)v[j];
          float av = p.al[cbase + j];
          float rv = p.ar[cbase + j];
          if (((i * 8 + j) >> 5) == 0) { e0 = fmaf(f, av, e0); r0 = fmaf(f, rv, r0); }
          else                         { e1 = fmaf(f, av, e1); r1 = fmaf(f, rv, r1); }
        }
      }
      *(float2*)(p.el + (size_t)row * 4 + half * 2) = make_float2(e0, e1);
      *(float2*)(p.er + (size_t)row * 4 + half * 2) = make_float2(r0, r1);
    }
  }
}

template <int AFP16>
__global__ __launch_bounds__(256) void gemm_kernel(GemmP p0, GemmP p1, int n) {
  gemm_body<AFP16>(blockIdx.y ? p1 : p0, blockIdx.x, n);
}

// hist || gemm0 fused: blocks [0, 2*gg) run the layer-0 GEMM (both channels,
// scheduled first -- long tiles grab CUs early); blocks [2*gg, ...) run hist
// (one 256-edge chunk each; fire-and-forget atomics + rank store tolerate
// the fused kernel's VGPR/LDS occupancy cost).
__global__ __launch_bounds__(256) void hist_gemm0_kernel(
    GemmP p0, GemmP p1, int gg, int n,
    const int* __restrict__ dst, int* __restrict__ counts,
    int* __restrict__ rank, int E) {
  int b = blockIdx.x;
  if (b < 2 * gg) {
    gemm_body<0>((b >= gg) ? p1 : p0, (b >= gg) ? b - gg : b, n);
    return;
  }
  int e = (b - 2 * gg) * 256 + threadIdx.x;
  if (e < E) rank[e] = atomicAdd(&counts[dst[e]], 1);
}

// One wave per (node, channel). Block = 4 waves = 2 nodes x 2 channels.
// Fused lane-parallel coef (lane h*16+e computes one (edge,head) exp),
// redistributed with __shfl(x, j, 16). Per-channel 8B edge recs {src, w}.
template <int LAYER>
__global__ __launch_bounds__(256) void gather_kernel(ChP c0, ChP c1,
                                                     const int* __restrict__ offs, int n) {
  int t = threadIdx.x;
  int w = t >> 6;
  int lane = t & 63;
  int node = blockIdx.x * 2 + (w >> 1);
  int ch = w & 1;
  if (node >= n) return;  // wave-uniform
  ChP P = ch ? c1 : c0;
  int hh = lane >> 4;   // head (both phases)
  int ce = lane & 7;    // edge slot (coef phase)

  int start = __builtin_amdgcn_readfirstlane(offs[node]);
  int end = __builtin_amdgcn_readfirstlane(offs[node + 1]);
  float er_h = P.er[(size_t)node * 4 + hh];
  const __half2* ftbase = (const __half2*)P.ft;
  const float* elb = P.el;
  const int2* edb = P.ed;
  const int* e32 = (const int*)edb;

  float acc0 = 0.f, acc1 = 0.f, l = 0.f;
  int k = start;
  while (k + 8 <= end) {
    int2 ed[8];
#pragma unroll
    for (int j = 0; j < 8; ++j) ed[j] = edb[k + j];  // uniform -> SGPR
    // ---- lane-parallel coef: one (edge,head) exp per lane ----
    int s_v = e32[(size_t)(k + ce) * 2];            // src of edge slot ce
    float el_v = elb[(size_t)s_v * 4 + hh];         // gather (L2-resident)
    float ev = el_v + er_h;
    ev = (ev > 0.f) ? ev : 0.2f * ev;
    float x_v = __expf(ev);
    // ---- MAC phase ----
#pragma unroll
    for (int j = 0; j < 8; ++j) {
      int s = ed[j].x;  // uniform -> SGPR
      float wgt = __int_as_float(ed[j].y);
      __half2 fh = ftbase[(size_t)s * 64 + lane];   // saddr + lane*4
      float x = __shfl(x_v, j, 16);                 // x[j][hh]
      l += x;
      float cv = x * wgt;
      acc0 = fmaf(cv, __low2float(fh), acc0);
      acc1 = fmaf(cv, __high2float(fh), acc1);
    }
    k += 8;
  }
  for (; k < end; ++k) {  // tail: wave-redundant exp (<=7 edges)
    int2 ed = edb[k];
    int s = ed.x;
    float wgt = __int_as_float(ed.y);
    float el_s = elb[(size_t)s * 4 + hh];
    float ev = el_s + er_h;
    ev = (ev > 0.f) ? ev : 0.2f * ev;
    float x = __expf(ev);
    __half2 fh = ftbase[(size_t)s * 64 + lane];
    l += x;
    float cv = x * wgt;
    acc0 = fmaf(cv, __low2float(fh), acc0);
    acc1 = fmaf(cv, __high2float(fh), acc1);
  }

  float rl = 1.f / fmaxf(l, 1e-9f);
  float2 b2 = *(const float2*)(P.bias + lane * 2);
  float v0 = fmaf(acc0, rl, b2.x);
  float v1 = fmaf(acc1, rl, b2.y);
  if (LAYER == 0) {
    // fp16 hidden buffer (GEMM-1 would quantize to fp16 anyway)
    __half2 h = __floats2half2_rn(fmaxf(v0, 0.f), fmaxf(v1, 0.f));
    ((__half2*)P.out)[(size_t)node * 64 + lane] = h;
  } else {
    v0 += __shfl_xor(v0, 16); v1 += __shfl_xor(v1, 16);
    v0 += __shfl_xor(v0, 32); v1 += __shfl_xor(v1, 32);
    if (lane < 16) {
      *(float2*)((float*)P.out + (size_t)node * 32 + lane * 2) =
          make_float2(0.25f * v0, 0.25f * v1);
    }
  }
}

extern "C" void kernel_launch(void* const* d_in, const int* in_sizes, int n_in,
                              void* d_out, int out_size, void* d_ws, size_t ws_size,
                              hipStream_t stream) {
  const float* x_am = (const float*)d_in[0];
  const float* x_ph = (const float*)d_in[1];
  const float* exist = (const float*)d_in[2];
  const float* am_exist = (const float*)d_in[3];
  const int* src = (const int*)d_in[4];
  const int* dst = (const int*)d_in[5];
  const float* W0a = (const float*)d_in[6];
  const float* al0a = (const float*)d_in[7];
  const float* ar0a = (const float*)d_in[8];
  const float* b0a = (const float*)d_in[9];
  const float* W0p = (const float*)d_in[10];
  const float* al0p = (const float*)d_in[11];
  const float* ar0p = (const float*)d_in[12];
  const float* b0p = (const float*)d_in[13];
  const float* W1a = (const float*)d_in[14];
  const float* al1a = (const float*)d_in[15];
  const float* ar1a = (const float*)d_in[16];
  const float* b1a = (const float*)d_in[17];
  const float* W1p = (const float*)d_in[18];
  const float* al1p = (const float*)d_in[19];
  const float* ar1p = (const float*)d_in[20];
  const float* b1p = (const float*)d_in[21];

  int n = in_sizes[0] / 128;  // 50000
  int E = in_sizes[2];        // 800000
  int N_pad = (n + 255) & ~255;
  int nb = (n + 255) / 256;
  int NB_pad = (nb + 63) & ~63;

  size_t szN = (size_t)N_pad * 4;
  size_t szSync = (size_t)(64 + 3 * NB_pad) * 4;
  size_t szRank = (size_t)E * 4;
  size_t szOffs = (size_t)(N_pad + 8) * 4;
  size_t szE8 = (size_t)E * 8;          // per-channel {src, w} recs
  size_t szFt16 = (size_t)n * 128 * 2;  // fp16 ft / hb
  size_t szEl = (size_t)N_pad * 4 * 4;
  size_t szWt = (size_t)4 * 128 * 128 * 2;

  auto rnd = [](size_t b) { return (b + 255) & ~(size_t)255; };
  size_t fixed = rnd(szN) + rnd(szSync) + rnd(szRank) + rnd(szOffs) + 2 * rnd(szE8) +
                 4 * rnd(szEl) + rnd(szWt);
  bool dual = ws_size >= fixed + 4 * rnd(szFt16);

  char* p = (char*)d_ws;
  auto take = [&](size_t b) { char* q = p; p += (b + 255) & ~(size_t)255; return q; };
  int* counts = (int*)take(szN);
  int* sync = (int*)take(szSync);  // adjacent to counts: one zero pass covers both
  int* rank = (int*)take(szRank);
  int* offs = (int*)take(szOffs);
  int2* am8 = (int2*)take(szE8);
  int2* ph8 = (int2*)take(szE8);
  __half* Wt = (__half*)take(szWt);
  float* el_am = (float*)take(szEl);
  float* el_ph = (float*)take(szEl);
  float* er_am = (float*)take(szEl);
  float* er_ph = (float*)take(szEl);
  __half* ft_am = (__half*)take(szFt16);
  __half* ft_ph = dual ? (__half*)take(szFt16) : ft_am;
  __half* hb_am = (__half*)take(szFt16);
  __half* hb_ph = dual ? (__half*)take(szFt16) : hb_am;

  float* out_am = (float*)d_out;
  float* out_ph = out_am + (size_t)n * 32;

  int nzero = (int)((rnd(szN) + rnd(szSync)) / 4);  // 51,008 ints < 65,536
  int gg = (n + 127) / 128;
  int gw = (n + 1) / 2;
  int nhb = (E + 255) / 256;
  GemmP g0a{x_am, Wt,          al0a, ar0a, ft_am, el_am, er_am};
  GemmP g0p{x_ph, Wt + 16384,  al0p, ar0p, ft_ph, el_ph, er_ph};
  GemmP g1a{hb_am, Wt + 32768, al1a, ar1a, ft_am, el_am, er_am};
  GemmP g1p{hb_ph, Wt + 49152, al1p, ar1p, ft_ph, el_ph, er_ph};
  ChP c0a{ft_am, el_am, er_am, b0a, am8, hb_am};
  ChP c0p{ft_ph, el_ph, er_ph, b0p, ph8, hb_ph};
  ChP c1a{ft_am, el_am, er_am, b1a, am8, out_am};
  ChP c1p{ft_ph, el_ph, er_ph, b1p, ph8, out_ph};

  init_kernel<<<256, 256, 0, stream>>>(counts, nzero, W0a, W0p, W1a, W1p, Wt);

  if (dual) {
    hist_gemm0_kernel<<<2 * gg + nhb, 256, 0, stream>>>(g0a, g0p, gg, n,
                                                        dst, counts, rank, E);
    scan_kernel<<<nb, 256, 0, stream>>>(counts, offs, sync, NB_pad, n, E);
    fill_kernel<<<nhb, 256, 0, stream>>>(src, dst, exist, am_exist, offs, rank,
                                         am8, ph8, E);
    gather_kernel<0><<<gw, 256, 0, stream>>>(c0a, c0p, offs, n);
    gemm_kernel<1><<<dim3(gg, 2), 256, 0, stream>>>(g1a, g1p, n);
    gather_kernel<1><<<gw, 256, 0, stream>>>(c1a, c1p, offs, n);
  } else {
    // sequential fallback: both halves run the same channel (duplicate
    // identical writes, benign); buffers aliased above.
    hist_gemm0_kernel<<<2 * gg + nhb, 256, 0, stream>>>(g0a, g0a, gg, n,
                                                        dst, counts, rank, E);
    scan_kernel<<<nb, 256, 0, stream>>>(counts, offs, sync, NB_pad, n, E);
    fill_kernel<<<nhb, 256, 0, stream>>>(src, dst, exist, am_exist, offs, rank,
                                         am8, ph8, E);
    gather_kernel<0><<<gw, 256, 0, stream>>>(c0a, c0a, offs, n);
    gemm_kernel<1><<<dim3(gg, 2), 256, 0, stream>>>(g1a, g1a, n);
    gather_kernel<1><<<gw, 256, 0, stream>>>(c1a, c1a, offs, n);
    gemm_kernel<0><<<dim3(gg, 2), 256, 0, stream>>>(g0p, g0p, n);
    gather_kernel<0><<<gw, 256, 0, stream>>>(c0p, c0p, offs, n);
    gemm_kernel<1><<<dim3(gg, 2), 256, 0, stream>>>(g1p, g1p, n);
    gather_kernel<1><<<gw, 256, 0, stream>>>(c1p, c1p, offs, n);
  }
}

// Round 11
// 382.806 us; speedup vs baseline: 1.1070x; 1.1070x over previous
//
#include <hip/hip_runtime.h>
#include <hip/hip_fp16.h>

// ---------------------------------------------------------------------------
// DUPLEX GAT, round 19 = r17 gather/fill + r18 schedule.
//   - EDGE-SPLIT REVERTED: 16B int4 edge16 recs again. r18's per-channel 8B
//     split lost 29us: killed cross-channel line sharing (both ch-waves read
//     the same edge16 lines; 2nd was a cache hit) and demoted record loads
//     from the scalar pipe (SGPR 64->48) onto the vmcnt queue.
//   - Schedule (r18, kept; inferred +8us): init (zero+wprep) -> hist||gemm0
//     (independent; gemm blocks first, hist's fire-and-forget atomics
//     tolerate occupancy cost) -> scan -> fill -> gather0 -> gemm1 -> gather1.
//   - fill: atomic-free via rank-from-hist (r17 win).
//   - gather: r13 fused lane-parallel coef shape (best measured, 75.7us).
//   - 7 dispatches: init, hist||gemm0, scan, fill, gather0, gemm1, gather1.
// ---------------------------------------------------------------------------

typedef _Float16 f16x8 __attribute__((ext_vector_type(8)));
typedef float f32x4 __attribute__((ext_vector_type(4)));

struct GemmP { const void* X; const __half* Wt; const float *al, *ar; __half* Y; float *el, *er; };
struct ChP   { const __half* ft; const float *el, *er, *bias; void* out; };

// Zero the counts+sync region AND convert/transpose the 4 weight matrices
// (Wt_m[nn][k] = half(W_m[k][nn])). Replaces hipMemsetAsync + in-hist wprep.
__global__ void init_kernel(int* __restrict__ zero, int nzero,
                            const float* __restrict__ W0a, const float* __restrict__ W0p,
                            const float* __restrict__ W1a, const float* __restrict__ W1p,
                            __half* __restrict__ Wt) {
  int i = blockIdx.x * 256 + threadIdx.x;  // grid = 256 blocks = 65536 threads
  if (i < nzero) zero[i] = 0;
  {
    int m = i >> 14, idx = i & 16383;
    const float* W = (m == 0) ? W0a : (m == 1) ? W0p : (m == 2) ? W1a : W1p;
    int nn = idx >> 7, k = idx & 127;
    Wt[(size_t)m * 16384 + nn * 128 + k] = __float2half_rn(W[k * 128 + nn]);
  }
}

// Single-pass exclusive scan, wave-parallel decoupled lookback.
// sync layout (ints): [0]=ticket; state[nb_stride] @ +64; agg @ +64+nb_stride;
// incl @ +64+2*nb_stride. All zeroed by init.
__global__ __launch_bounds__(256) void scan_kernel(const int* __restrict__ counts,
                                                   int* __restrict__ offsets,
                                                   int* __restrict__ sync,
                                                   int nb_stride, int n, int E) {
  __shared__ int lds[256];
  __shared__ int sbid, sprev;
  int* state = sync + 64;
  int* agg = state + nb_stride;
  int* incl = agg + nb_stride;
  int t = threadIdx.x;
  if (t == 0) sbid = atomicAdd(sync, 1);
  __syncthreads();
  int bid = sbid;
  int i = bid * 256 + t;
  int v = (i < n) ? counts[i] : 0;
  lds[t] = v;
  __syncthreads();
  for (int off = 1; off < 256; off <<= 1) {
    int x = (t >= off) ? lds[t - off] : 0;
    __syncthreads();
    lds[t] += x;
    __syncthreads();
  }
  int total = lds[255];
  if (t == 0) {
    if (bid == 0) {
      __hip_atomic_store(&incl[0], total, __ATOMIC_RELAXED, __HIP_MEMORY_SCOPE_AGENT);
      __hip_atomic_store(&state[0], 2, __ATOMIC_RELEASE, __HIP_MEMORY_SCOPE_AGENT);
      sprev = 0;
    } else {
      __hip_atomic_store(&agg[bid], total, __ATOMIC_RELAXED, __HIP_MEMORY_SCOPE_AGENT);
      __hip_atomic_store(&state[bid], 1, __ATOMIC_RELEASE, __HIP_MEMORY_SCOPE_AGENT);
    }
  }
  if (bid > 0 && t < 64) {  // wave 0: windowed lookback, 64 predecessors/round
    int run = 0;
    int base = bid - 1;
    while (true) {
      int idx = base - t;
      int st = 2, val = 0;
      if (idx >= 0) {
        do {
          st = __hip_atomic_load(&state[idx], __ATOMIC_ACQUIRE, __HIP_MEMORY_SCOPE_AGENT);
        } while (st == 0);
        val = (st == 2)
                  ? __hip_atomic_load(&incl[idx], __ATOMIC_RELAXED, __HIP_MEMORY_SCOPE_AGENT)
                  : __hip_atomic_load(&agg[idx], __ATOMIC_RELAXED, __HIP_MEMORY_SCOPE_AGENT);
      }
      unsigned long long done = __ballot(st == 2);
      int firstDone = (int)__ffsll(done) - 1;  // nearest block with inclusive prefix
      int contrib = (firstDone < 0) ? val : ((t <= firstDone) ? val : 0);
#pragma unroll
      for (int o = 1; o < 64; o <<= 1) contrib += __shfl_xor(contrib, o);
      run += contrib;
      if (firstDone >= 0) break;
      base -= 64;
    }
    if (t == 0) {
      __hip_atomic_store(&incl[bid], run + total, __ATOMIC_RELAXED, __HIP_MEMORY_SCOPE_AGENT);
      __hip_atomic_store(&state[bid], 2, __ATOMIC_RELEASE, __HIP_MEMORY_SCOPE_AGENT);
      sprev = run;
    }
  }
  __syncthreads();
  int prev = sprev;
  if (i < n) offsets[i] = prev + lds[t] - v;  // exclusive
  if (i == 0) offsets[n] = E;
}

// Atomic-free fill: pos = offs[dst] + rank[e]. Pure loads -> one scattered
// 16B store; no dependent latency chain.
__global__ void fill_kernel(const int* __restrict__ src, const int* __restrict__ dst,
                            const float* __restrict__ exist, const float* __restrict__ am_exist,
                            const int* __restrict__ offs, const int* __restrict__ rank,
                            int4* __restrict__ edge16, int E) {
  int e = blockIdx.x * blockDim.x + threadIdx.x;
  if (e >= E) return;
  int d = dst[e];
  int pos = offs[d] + rank[e];
  edge16[pos] = make_int4(src[e], d, __float_as_int(am_exist[e]), __float_as_int(exist[e]));
}

// Y(fp16) = fp16(X) @ fp16(W), fp32 MFMA acc; fused fp32 el/er epilogue.
// AFP16: A operand already fp16 (layer 1) vs fp32->fp16 staging (layer 0).
template <int AFP16>
__device__ __forceinline__ void gemm_body(GemmP p, int bx, int n) {
  constexpr int LDH = 72;   // staging stride (halves)
  constexpr int LDE = 136;  // epilogue stride (halves)
  __shared__ __half lds[2 * 128 * LDH];  // 36,864 B
  __half* As = lds;
  __half* Ws = lds + 128 * LDH;
  int t = threadIdx.x;
  int row0 = bx << 7;
  int wv = t >> 6, lane = t & 63;
  int m = lane & 15, q = lane >> 4;

  f32x4 acc[2][8];
#pragma unroll
  for (int rt = 0; rt < 2; ++rt)
#pragma unroll
    for (int ct = 0; ct < 8; ++ct) acc[rt][ct] = (f32x4){0.f, 0.f, 0.f, 0.f};

#pragma unroll
  for (int kh = 0; kh < 2; ++kh) {
    __syncthreads();  // protect previous phase's fragment reads
    if (AFP16) {
      const __half* Xh = (const __half*)p.X;
#pragma unroll
      for (int i = 0; i < 4; ++i) {
        int c = t + (i << 8);  // 0..1023 chunks of 8 halves
        int r = c >> 3, o8 = c & 7;
        uint4 v = make_uint4(0, 0, 0, 0);
        if (row0 + r < n)
          v = *(const uint4*)(Xh + (size_t)(row0 + r) * 128 + (kh << 6) + (o8 << 3));
        *(uint4*)(As + r * LDH + (o8 << 3)) = v;
      }
    } else {
      const float* Xf = (const float*)p.X;
#pragma unroll
      for (int i = 0; i < 8; ++i) {
        int c = t + (i << 8);  // 0..2047 float4-chunks
        int r = c >> 4, f4 = c & 15;
        float4 v = make_float4(0.f, 0.f, 0.f, 0.f);
        if (row0 + r < n)
          v = *(const float4*)(Xf + (size_t)(row0 + r) * 128 + (kh << 6) + (f4 << 2));
        union { __half h[4]; uint2 u; } pk;
        pk.h[0] = __float2half_rn(v.x); pk.h[1] = __float2half_rn(v.y);
        pk.h[2] = __float2half_rn(v.z); pk.h[3] = __float2half_rn(v.w);
        *(uint2*)(As + r * LDH + (f4 << 2)) = pk.u;
      }
    }
    // stage Wt: 128 n-rows x 64 k (already fp16)
#pragma unroll
    for (int i = 0; i < 4; ++i) {
      int c = t + (i << 8);
      int r = c >> 3, o8 = c & 7;
      uint4 v = *(const uint4*)(p.Wt + (size_t)r * 128 + (kh << 6) + (o8 << 3));
      *(uint4*)(Ws + r * LDH + (o8 << 3)) = v;
    }
    __syncthreads();
#pragma unroll
    for (int kc = 0; kc < 2; ++kc) {
      f16x8 a0 = *(const f16x8*)(As + (wv * 32 + m) * LDH + kc * 32 + q * 8);
      f16x8 a1 = *(const f16x8*)(As + (wv * 32 + 16 + m) * LDH + kc * 32 + q * 8);
#pragma unroll
      for (int ct = 0; ct < 8; ++ct) {
        f16x8 b = *(const f16x8*)(Ws + (ct * 16 + m) * LDH + kc * 32 + q * 8);
        acc[0][ct] = __builtin_amdgcn_mfma_f32_16x16x32_f16(a0, b, acc[0][ct], 0, 0, 0);
        acc[1][ct] = __builtin_amdgcn_mfma_f32_16x16x32_f16(a1, b, acc[1][ct], 0, 0, 0);
      }
    }
  }
  // ---- epilogue: acc -> LDS fp16 (C/D layout: col=lane&15, row=quad*4+reg) ----
  __syncthreads();
#pragma unroll
  for (int rt = 0; rt < 2; ++rt) {
    int rbase = wv * 32 + rt * 16 + q * 4;
#pragma unroll
    for (int ct = 0; ct < 8; ++ct) {
      int col = ct * 16 + m;
#pragma unroll
      for (int r = 0; r < 4; ++r)
        lds[(rbase + r) * LDE + col] = __float2half_rn(acc[rt][ct][r]);
    }
  }
  __syncthreads();
  // 2 threads per row: half = cols 0..63 / 64..127. ft store + el/er head-dots.
  {
    int r = t & 127;
    int half = t >> 7;
    int row = row0 + r;
    if (row < n) {
      float e0 = 0.f, e1 = 0.f, r0 = 0.f, r1 = 0.f;
#pragma unroll
      for (int i = 0; i < 8; ++i) {
        int cbase = half * 64 + i * 8;
        f16x8 v = *(const f16x8*)(lds + r * LDE + cbase);
        *(uint4*)(p.Y + (size_t)row * 128 + cbase) = *(const uint4*)&v;
#pragma unroll
        for (int j = 0; j < 8; ++j) {
          float f = (float)v[j];
          float av = p.al[cbase + j];
          float rv = p.ar[cbase + j];
          if (((i * 8 + j) >> 5) == 0) { e0 = fmaf(f, av, e0); r0 = fmaf(f, rv, r0); }
          else                         { e1 = fmaf(f, av, e1); r1 = fmaf(f, rv, r1); }
        }
      }
      *(float2*)(p.el + (size_t)row * 4 + half * 2) = make_float2(e0, e1);
      *(float2*)(p.er + (size_t)row * 4 + half * 2) = make_float2(r0, r1);
    }
  }
}

template <int AFP16>
__global__ __launch_bounds__(256) void gemm_kernel(GemmP p0, GemmP p1, int n) {
  gemm_body<AFP16>(blockIdx.y ? p1 : p0, blockIdx.x, n);
}

// hist || gemm0 fused: blocks [0, 2*gg) run the layer-0 GEMM (both channels,
// scheduled first -- long tiles grab CUs early); blocks [2*gg, ...) run hist
// (one 256-edge chunk each; fire-and-forget atomics + rank store tolerate
// the fused kernel's VGPR/LDS occupancy cost).
__global__ __launch_bounds__(256) void hist_gemm0_kernel(
    GemmP p0, GemmP p1, int gg, int n,
    const int* __restrict__ dst, int* __restrict__ counts,
    int* __restrict__ rank, int E) {
  int b = blockIdx.x;
  if (b < 2 * gg) {
    gemm_body<0>((b >= gg) ? p1 : p0, (b >= gg) ? b - gg : b, n);
    return;
  }
  int e = (b - 2 * gg) * 256 + threadIdx.x;
  if (e < E) rank[e] = atomicAdd(&counts[dst[e]], 1);
}

// One wave per (node, channel). Block = 4 waves = 2 nodes x 2 channels.
// Fused lane-parallel coef (lane h*16+e computes one (edge,head) exp),
// redistributed with __shfl(x, j, 16). 16B shared edge recs (both channels
// read the same lines -> second wave hits cache; scalar-pipe record loads).
template <int LAYER>
__global__ __launch_bounds__(256) void gather_kernel(ChP c0, ChP c1,
                                                     const int* __restrict__ offs,
                                                     const int4* __restrict__ edge16, int n) {
  int t = threadIdx.x;
  int w = t >> 6;
  int lane = t & 63;
  int node = blockIdx.x * 2 + (w >> 1);
  int ch = w & 1;
  if (node >= n) return;  // wave-uniform
  ChP P = ch ? c1 : c0;
  int hh = lane >> 4;   // head (both phases)
  int ce = lane & 7;    // edge slot (coef phase)

  int start = __builtin_amdgcn_readfirstlane(offs[node]);
  int end = __builtin_amdgcn_readfirstlane(offs[node + 1]);
  float er_h = P.er[(size_t)node * 4 + hh];
  const __half2* ftbase = (const __half2*)P.ft;
  const float* elb = P.el;
  const int* e32 = (const int*)edge16;

  float acc0 = 0.f, acc1 = 0.f, l = 0.f;
  int k = start;
  while (k + 8 <= end) {
    int4 ed[8];
#pragma unroll
    for (int j = 0; j < 8; ++j) ed[j] = edge16[k + j];  // uniform -> SGPR
    // ---- lane-parallel coef: one (edge,head) exp per lane ----
    int s_v = e32[(size_t)(k + ce) * 4];            // src of edge slot ce
    float el_v = elb[(size_t)s_v * 4 + hh];         // gather (L2-resident)
    float ev = el_v + er_h;
    ev = (ev > 0.f) ? ev : 0.2f * ev;
    float x_v = __expf(ev);
    // ---- MAC phase ----
#pragma unroll
    for (int j = 0; j < 8; ++j) {
      int s = ed[j].x;  // uniform -> SGPR
      float wgt = __int_as_float(ch ? ed[j].w : ed[j].z);
      __half2 fh = ftbase[(size_t)s * 64 + lane];   // saddr + lane*4
      float x = __shfl(x_v, j, 16);                 // x[j][hh]
      l += x;
      float cv = x * wgt;
      acc0 = fmaf(cv, __low2float(fh), acc0);
      acc1 = fmaf(cv, __high2float(fh), acc1);
    }
    k += 8;
  }
  for (; k < end; ++k) {  // tail: wave-redundant exp (<=7 edges)
    int4 ed = edge16[k];
    int s = ed.x;
    float wgt = __int_as_float(ch ? ed.w : ed.z);
    float el_s = elb[(size_t)s * 4 + hh];
    float ev = el_s + er_h;
    ev = (ev > 0.f) ? ev : 0.2f * ev;
    float x = __expf(ev);
    __half2 fh = ftbase[(size_t)s * 64 + lane];
    l += x;
    float cv = x * wgt;
    acc0 = fmaf(cv, __low2float(fh), acc0);
    acc1 = fmaf(cv, __high2float(fh), acc1);
  }

  float rl = 1.f / fmaxf(l, 1e-9f);
  float2 b2 = *(const float2*)(P.bias + lane * 2);
  float v0 = fmaf(acc0, rl, b2.x);
  float v1 = fmaf(acc1, rl, b2.y);
  if (LAYER == 0) {
    // fp16 hidden buffer (GEMM-1 would quantize to fp16 anyway)
    __half2 h = __floats2half2_rn(fmaxf(v0, 0.f), fmaxf(v1, 0.f));
    ((__half2*)P.out)[(size_t)node * 64 + lane] = h;
  } else {
    v0 += __shfl_xor(v0, 16); v1 += __shfl_xor(v1, 16);
    v0 += __shfl_xor(v0, 32); v1 += __shfl_xor(v1, 32);
    if (lane < 16) {
      *(float2*)((float*)P.out + (size_t)node * 32 + lane * 2) =
          make_float2(0.25f * v0, 0.25f * v1);
    }
  }
}

extern "C" void kernel_launch(void* const* d_in, const int* in_sizes, int n_in,
                              void* d_out, int out_size, void* d_ws, size_t ws_size,
                              hipStream_t stream) {
  const float* x_am = (const float*)d_in[0];
  const float* x_ph = (const float*)d_in[1];
  const float* exist = (const float*)d_in[2];
  const float* am_exist = (const float*)d_in[3];
  const int* src = (const int*)d_in[4];
  const int* dst = (const int*)d_in[5];
  const float* W0a = (const float*)d_in[6];
  const float* al0a = (const float*)d_in[7];
  const float* ar0a = (const float*)d_in[8];
  const float* b0a = (const float*)d_in[9];
  const float* W0p = (const float*)d_in[10];
  const float* al0p = (const float*)d_in[11];
  const float* ar0p = (const float*)d_in[12];
  const float* b0p = (const float*)d_in[13];
  const float* W1a = (const float*)d_in[14];
  const float* al1a = (const float*)d_in[15];
  const float* ar1a = (const float*)d_in[16];
  const float* b1a = (const float*)d_in[17];
  const float* W1p = (const float*)d_in[18];
  const float* al1p = (const float*)d_in[19];
  const float* ar1p = (const float*)d_in[20];
  const float* b1p = (const float*)d_in[21];

  int n = in_sizes[0] / 128;  // 50000
  int E = in_sizes[2];        // 800000
  int N_pad = (n + 255) & ~255;
  int nb = (n + 255) / 256;
  int NB_pad = (nb + 63) & ~63;

  size_t szN = (size_t)N_pad * 4;
  size_t szSync = (size_t)(64 + 3 * NB_pad) * 4;
  size_t szRank = (size_t)E * 4;
  size_t szOffs = (size_t)(N_pad + 8) * 4;
  size_t szE16 = (size_t)E * 16;
  size_t szFt16 = (size_t)n * 128 * 2;  // fp16 ft / hb
  size_t szEl = (size_t)N_pad * 4 * 4;
  size_t szWt = (size_t)4 * 128 * 128 * 2;

  auto rnd = [](size_t b) { return (b + 255) & ~(size_t)255; };
  size_t fixed = rnd(szN) + rnd(szSync) + rnd(szRank) + rnd(szOffs) + rnd(szE16) +
                 4 * rnd(szEl) + rnd(szWt);
  bool dual = ws_size >= fixed + 4 * rnd(szFt16);

  char* p = (char*)d_ws;
  auto take = [&](size_t b) { char* q = p; p += (b + 255) & ~(size_t)255; return q; };
  int* counts = (int*)take(szN);
  int* sync = (int*)take(szSync);  // adjacent to counts: one zero pass covers both
  int* rank = (int*)take(szRank);
  int* offs = (int*)take(szOffs);
  int4* edge16 = (int4*)take(szE16);
  __half* Wt = (__half*)take(szWt);
  float* el_am = (float*)take(szEl);
  float* el_ph = (float*)take(szEl);
  float* er_am = (float*)take(szEl);
  float* er_ph = (float*)take(szEl);
  __half* ft_am = (__half*)take(szFt16);
  __half* ft_ph = dual ? (__half*)take(szFt16) : ft_am;
  __half* hb_am = (__half*)take(szFt16);
  __half* hb_ph = dual ? (__half*)take(szFt16) : hb_am;

  float* out_am = (float*)d_out;
  float* out_ph = out_am + (size_t)n * 32;

  int nzero = (int)((rnd(szN) + rnd(szSync)) / 4);  // 51,008 ints < 65,536
  int gg = (n + 127) / 128;
  int gw = (n + 1) / 2;
  int nhb = (E + 255) / 256;
  GemmP g0a{x_am, Wt,          al0a, ar0a, ft_am, el_am, er_am};
  GemmP g0p{x_ph, Wt + 16384,  al0p, ar0p, ft_ph, el_ph, er_ph};
  GemmP g1a{hb_am, Wt + 32768, al1a, ar1a, ft_am, el_am, er_am};
  GemmP g1p{hb_ph, Wt + 49152, al1p, ar1p, ft_ph, el_ph, er_ph};
  ChP c0a{ft_am, el_am, er_am, b0a, hb_am};
  ChP c0p{ft_ph, el_ph, er_ph, b0p, hb_ph};
  ChP c1a{ft_am, el_am, er_am, b1a, out_am};
  ChP c1p{ft_ph, el_ph, er_ph, b1p, out_ph};

  init_kernel<<<256, 256, 0, stream>>>(counts, nzero, W0a, W0p, W1a, W1p, Wt);

  if (dual) {
    hist_gemm0_kernel<<<2 * gg + nhb, 256, 0, stream>>>(g0a, g0p, gg, n,
                                                        dst, counts, rank, E);
    scan_kernel<<<nb, 256, 0, stream>>>(counts, offs, sync, NB_pad, n, E);
    fill_kernel<<<nhb, 256, 0, stream>>>(src, dst, exist, am_exist, offs, rank,
                                         edge16, E);
    gather_kernel<0><<<gw, 256, 0, stream>>>(c0a, c0p, offs, edge16, n);
    gemm_kernel<1><<<dim3(gg, 2), 256, 0, stream>>>(g1a, g1p, n);
    gather_kernel<1><<<gw, 256, 0, stream>>>(c1a, c1p, offs, edge16, n);
  } else {
    // sequential fallback: both halves run the same channel (duplicate
    // identical writes, benign); buffers aliased above.
    hist_gemm0_kernel<<<2 * gg + nhb, 256, 0, stream>>>(g0a, g0a, gg, n,
                                                        dst, counts, rank, E);
    scan_kernel<<<nb, 256, 0, stream>>>(counts, offs, sync, NB_pad, n, E);
    fill_kernel<<<nhb, 256, 0, stream>>>(src, dst, exist, am_exist, offs, rank,
                                         edge16, E);
    gather_kernel<0><<<gw, 256, 0, stream>>>(c0a, c0a, offs, edge16, n);
    gemm_kernel<1><<<dim3(gg, 2), 256, 0, stream>>>(g1a, g1a, n);
    gather_kernel<1><<<gw, 256, 0, stream>>>(c1a, c1a, offs, edge16, n);
    gemm_kernel<0><<<dim3(gg, 2), 256, 0, stream>>>(g0p, g0p, n);
    gather_kernel<0><<<gw, 256, 0, stream>>>(c0p, c0p, offs, edge16, n);
    gemm_kernel<1><<<dim3(gg, 2), 256, 0, stream>>>(g1p, g1p, n);
    gather_kernel<1><<<gw, 256, 0, stream>>>(c1p, c1p, offs, edge16, n);
  }
}